// Round 1
// baseline (3527.497 us; speedup 1.0000x reference)
//
#include <hip/hip_runtime.h>
#include <hip/hip_bf16.h>

#define VOCAB 50257
#define EMBD  256
#define HID   512
#define BATCH 64
#define SEQ   512
#define NG    32     // workgroups per batch-group (each owns 16 h-cols)
#define NGRP  4      // batch groups of 16 rows

typedef short bf16x8 __attribute__((ext_vector_type(8)));
typedef float f32x4  __attribute__((ext_vector_type(4)));

__device__ inline short f2b(float f) {            // RNE float->bf16
    union { float f; unsigned u; } v; v.f = f;
    unsigned r = v.u + 0x7FFFu + ((v.u >> 16) & 1u);
    return (short)(r >> 16);
}
__device__ inline unsigned pack2_trunc(float lo, float hi) {  // 2 floats -> packed bf16x2 (truncate)
    union { float f; unsigned u; } a, b; a.f = lo; b.f = hi;
    return __builtin_amdgcn_perm(b.u, a.u, 0x07060302);
}
__device__ inline float fast_tanh(float x) {
    x = fminf(fmaxf(x, -15.f), 15.f);
    float e = __expf(2.f * x);
    return (e - 1.f) / (e + 1.f);
}
__device__ inline float fast_sig(float x) { return 1.f / (1.f + __expf(-x)); }

__device__ inline void load_x_frags(const float* __restrict__ emb, int idxv, int quad, bf16x8* Ax) {
#pragma unroll
    for (int kt = 0; kt < 8; ++kt) {
        const float* p = emb + (size_t)idxv * EMBD + kt * 32 + quad * 8;
        float4 e0 = *(const float4*)(p);
        float4 e1 = *(const float4*)(p + 4);
        union { bf16x8 v; unsigned u[4]; } f;
        f.u[0] = pack2_trunc(e0.x, e0.y);
        f.u[1] = pack2_trunc(e0.z, e0.w);
        f.u[2] = pack2_trunc(e1.x, e1.y);
        f.u[3] = pack2_trunc(e1.z, e1.w);
        Ax[kt] = f.v;
    }
}

// ---------------------------------------------------------------------------
// Persistent LSTM: 128 WGs = 4 groups (16 batch rows) x 32 WGs (16 h-cols).
// Wave g of a WG computes gate g (i|f|g|o) for its 16 h-cols via MFMA with
// register-resident Wh/Wi fragments. Per-step h exchange through L3 with
// relaxed agent atomics + per-group monotonic counter.
// ---------------------------------------------------------------------------
__global__ __launch_bounds__(256, 1) void lstm_kernel(
    const int* __restrict__ idx, const float* __restrict__ emb,
    const float* __restrict__ Wi, const float* __restrict__ Wh,
    const float* __restrict__ bvec, unsigned* __restrict__ ctr,
    unsigned short* __restrict__ hbuf /* [2][64][512] bf16 */)
{
    const int wgid = blockIdx.x;
    const int grp  = wgid >> 5;
    const int j    = wgid & 31;
    const int tid  = threadIdx.x;
    const int lane = tid & 63;
    const int gate = tid >> 6;         // wave id = gate (i,f,g,o)
    const int quad = lane >> 4;
    const int l16  = lane & 15;
    const int col  = gate * HID + j * 16 + l16;   // gate column in [0,2048)
    const int arow = grp * 16 + l16;              // batch row for A fragments

    __shared__ float gbuf[4][16][16];
    __shared__ float cstate[16][16];
    __shared__ __align__(16) unsigned short hstage[16][HID + 8];

    cstate[tid >> 4][tid & 15] = 0.f;

    // persistent B fragments: Wh slice (k=512) and Wi slice (k=256), RNE cvt
    bf16x8 Bh[16], Bx[8];
#pragma unroll
    for (int kt = 0; kt < 16; ++kt)
#pragma unroll
        for (int i = 0; i < 8; ++i)
            Bh[kt][i] = f2b(Wh[(size_t)(kt * 32 + quad * 8 + i) * 2048 + col]);
#pragma unroll
    for (int kt = 0; kt < 8; ++kt)
#pragma unroll
        for (int i = 0; i < 8; ++i)
            Bx[kt][i] = f2b(Wi[(size_t)(kt * 32 + quad * 8 + i) * 2048 + col]);
    const float bv = bvec[col];

    bf16x8 Ax[8];
    int idxv = idx[arow * SEQ];
    load_x_frags(emb, idxv, quad, Ax);

    unsigned* myctr = ctr + grp * 16;  // 64B-separated counters

    for (int t = 0; t < SEQ; ++t) {
        f32x4 acc = {0.f, 0.f, 0.f, 0.f};
#pragma unroll
        for (int kt = 0; kt < 8; ++kt)
            acc = __builtin_amdgcn_mfma_f32_16x16x32_bf16(Ax[kt], Bx[kt], acc, 0, 0, 0);

        int idxn = 0;
        if (t + 1 < SEQ) idxn = idx[arow * SEQ + t + 1];

        if (t > 0) {
            const unsigned target = (unsigned)(NG * t);
            while (__hip_atomic_load(myctr, __ATOMIC_RELAXED, __HIP_MEMORY_SCOPE_AGENT) < target) {}
            // cooperatively stage this group's h_t tile (16x512 bf16) into LDS
            const unsigned long long* hsrc = (const unsigned long long*)
                (hbuf + ((size_t)(t & 1) * BATCH + grp * 16) * HID);
            {
                const int r = tid >> 4, ch = tid & 15;
#pragma unroll
                for (int u = 0; u < 8; ++u) {
                    unsigned long long v = __hip_atomic_load(
                        (unsigned long long*)(hsrc + r * 128 + ch * 8 + u),
                        __ATOMIC_RELAXED, __HIP_MEMORY_SCOPE_AGENT);
                    *(unsigned long long*)&hstage[r][ch * 32 + u * 4] = v;
                }
            }
            __syncthreads();
#pragma unroll
            for (int kt = 0; kt < 16; ++kt) {
                bf16x8 a = *(const bf16x8*)&hstage[l16][kt * 32 + quad * 8];
                acc = __builtin_amdgcn_mfma_f32_16x16x32_bf16(a, Bh[kt], acc, 0, 0, 0);
            }
        }

        // activation: C layout row=(quad*4+r), col=l16
        float av[4];
#pragma unroll
        for (int r = 0; r < 4; ++r) {
            float z = acc[r] + bv;
            av[r] = (gate == 2) ? fast_tanh(z) : fast_sig(z);
        }
#pragma unroll
        for (int r = 0; r < 4; ++r)
            gbuf[gate][quad * 4 + r][l16] = av[r];
        __syncthreads();

        if (tid < 128) {  // c/h update: 2 cells per thread, 4B atomic store
            const int rr = tid >> 3, c2 = (tid & 7) * 2;
            float h0, h1;
            {
                float i0 = gbuf[0][rr][c2], f0 = gbuf[1][rr][c2];
                float g0 = gbuf[2][rr][c2], o0 = gbuf[3][rr][c2];
                float c = f0 * cstate[rr][c2] + i0 * g0;
                cstate[rr][c2] = c;
                h0 = o0 * fast_tanh(c);
            }
            {
                float i1 = gbuf[0][rr][c2 + 1], f1 = gbuf[1][rr][c2 + 1];
                float g1 = gbuf[2][rr][c2 + 1], o1 = gbuf[3][rr][c2 + 1];
                float c = f1 * cstate[rr][c2 + 1] + i1 * g1;
                cstate[rr][c2 + 1] = c;
                h1 = o1 * fast_tanh(c);
            }
            unsigned pv = (unsigned)(unsigned short)f2b(h0) |
                          ((unsigned)(unsigned short)f2b(h1) << 16);
            unsigned* dst = (unsigned*)(hbuf +
                ((size_t)((t + 1) & 1) * BATCH + grp * 16 + rr) * HID + j * 16 + c2);
            __hip_atomic_store(dst, pv, __ATOMIC_RELAXED, __HIP_MEMORY_SCOPE_AGENT);
        }
        __syncthreads();   // drains vmcnt: h stores complete at coherence point
        if (tid == 0)
            __hip_atomic_fetch_add(myctr, 1u, __ATOMIC_RELEASE, __HIP_MEMORY_SCOPE_AGENT);

        if (t + 1 < SEQ) {  // prefetch next x fragments (off critical path)
            idxv = idxn;
            load_x_frags(emb, idxv, quad, Ax);
        }
    }
}

// ---------------------------------------------------------------------------
// y = tanh(A[64x512](bf16) @ W[512x512](f32) + bias) -> out bf16 [64][512]
// grid 32 (16 cols each), wave = row tile
// ---------------------------------------------------------------------------
__global__ __launch_bounds__(256, 1) void gemm_tanh_kernel(
    const unsigned short* __restrict__ A, const float* __restrict__ W,
    const float* __restrict__ bias, unsigned short* __restrict__ out)
{
    const int tid = threadIdx.x, lane = tid & 63, wave = tid >> 6;
    const int quad = lane >> 4, l16 = lane & 15;
    const int col = blockIdx.x * 16 + l16;
    bf16x8 Bw[16];
#pragma unroll
    for (int kt = 0; kt < 16; ++kt)
#pragma unroll
        for (int i = 0; i < 8; ++i)
            Bw[kt][i] = f2b(W[(size_t)(kt * 32 + quad * 8 + i) * HID + col]);
    f32x4 acc = {0.f, 0.f, 0.f, 0.f};
#pragma unroll
    for (int kt = 0; kt < 16; ++kt) {
        bf16x8 a = *(const bf16x8*)(A + (size_t)(wave * 16 + l16) * HID + kt * 32 + quad * 8);
        acc = __builtin_amdgcn_mfma_f32_16x16x32_bf16(a, Bw[kt], acc, 0, 0, 0);
    }
    const float bvv = bias[col];
#pragma unroll
    for (int r = 0; r < 4; ++r) {
        float y = fast_tanh(acc[r] + bvv);
        out[(size_t)(wave * 16 + quad * 4 + r) * HID + col] = (unsigned short)f2b(y);
    }
}

// ---------------------------------------------------------------------------
// logits = A[64x512](bf16) @ W3[512x50257](f32) + b3 -> f32 [64][50257]
// grid ceil(50257/64), wave = 16-col tile, loop 4 row tiles
// ---------------------------------------------------------------------------
__global__ __launch_bounds__(256, 1) void logits_kernel(
    const unsigned short* __restrict__ A, const float* __restrict__ W3,
    const float* __restrict__ b3, float* __restrict__ outL)
{
    const int tid = threadIdx.x, lane = tid & 63, wave = tid >> 6;
    const int quad = lane >> 4, l16 = lane & 15;
    const int col = blockIdx.x * 64 + wave * 16 + l16;
    const int colc = (col < VOCAB) ? col : (VOCAB - 1);
    bf16x8 Bw[16];
#pragma unroll
    for (int kt = 0; kt < 16; ++kt)
#pragma unroll
        for (int i = 0; i < 8; ++i)
            Bw[kt][i] = f2b(W3[(size_t)(kt * 32 + quad * 8 + i) * VOCAB + colc]);
    const float bvv = b3[colc];
#pragma unroll
    for (int rt = 0; rt < 4; ++rt) {
        f32x4 acc = {0.f, 0.f, 0.f, 0.f};
#pragma unroll
        for (int kt = 0; kt < 16; ++kt) {
            bf16x8 a = *(const bf16x8*)(A + (size_t)(rt * 16 + l16) * HID + kt * 32 + quad * 8);
            acc = __builtin_amdgcn_mfma_f32_16x16x32_bf16(a, Bw[kt], acc, 0, 0, 0);
        }
        if (col < VOCAB) {
#pragma unroll
            for (int r = 0; r < 4; ++r)
                outL[(size_t)(rt * 16 + quad * 4 + r) * VOCAB + col] = acc[r] + bvv;
        }
    }
}

// ---------------------------------------------------------------------------
// row-wise log_softmax over [64][50257]
// ---------------------------------------------------------------------------
__global__ __launch_bounds__(256, 1) void lsm_kernel(
    const float* __restrict__ lg, float* __restrict__ out)
{
    const int row = blockIdx.x;
    const float* L = lg + (size_t)row * VOCAB;
    float m = -1e30f;
    for (int i = threadIdx.x; i < VOCAB; i += 256) m = fmaxf(m, L[i]);
#pragma unroll
    for (int o = 32; o; o >>= 1) m = fmaxf(m, __shfl_xor(m, o));
    __shared__ float red[4], red2[4];
    if ((threadIdx.x & 63) == 0) red[threadIdx.x >> 6] = m;
    __syncthreads();
    m = fmaxf(fmaxf(red[0], red[1]), fmaxf(red[2], red[3]));
    float s = 0.f;
    for (int i = threadIdx.x; i < VOCAB; i += 256) s += __expf(L[i] - m);
#pragma unroll
    for (int o = 32; o; o >>= 1) s += __shfl_xor(s, o);
    if ((threadIdx.x & 63) == 0) red2[threadIdx.x >> 6] = s;
    __syncthreads();
    s = red2[0] + red2[1] + red2[2] + red2[3];
    const float ls = m + __logf(s);
    float* O = out + (size_t)row * VOCAB;
    for (int i = threadIdx.x; i < VOCAB; i += 256) O[i] = L[i] - ls;
}

extern "C" void kernel_launch(void* const* d_in, const int* in_sizes, int n_in,
                              void* d_out, int out_size, void* d_ws, size_t ws_size,
                              hipStream_t stream) {
    (void)in_sizes; (void)n_in; (void)out_size; (void)ws_size;
    const int*   idx = (const int*)d_in[0];
    const float* emb = (const float*)d_in[1];
    const float* Wi  = (const float*)d_in[2];
    const float* Wh  = (const float*)d_in[3];
    const float* b   = (const float*)d_in[4];
    const float* W1  = (const float*)d_in[5];
    const float* b1  = (const float*)d_in[6];
    const float* W2  = (const float*)d_in[7];
    const float* b2  = (const float*)d_in[8];
    const float* W3  = (const float*)d_in[9];
    const float* b3  = (const float*)d_in[10];
    float* out = (float*)d_out;

    char* w = (char*)d_ws;
    unsigned*       ctr    = (unsigned*)w;                               // 256 B
    unsigned short* hbuf   = (unsigned short*)(w + 256);                 // 128 KiB
    unsigned short* y1     = (unsigned short*)(w + 256 + 131072);        // 64 KiB
    unsigned short* y2     = (unsigned short*)(w + 256 + 131072 + 65536);// 64 KiB
    float*          logits = (float*)(w + 256 + 131072 + 131072);        // 12.9 MB

    (void)hipMemsetAsync(ctr, 0, 256, stream);
    lstm_kernel<<<NGRP * NG, 256, 0, stream>>>(idx, emb, Wi, Wh, b, ctr, hbuf);
    gemm_tanh_kernel<<<HID / 16, 256, 0, stream>>>(hbuf, W1, b1, y1);  // hbuf slot 0 = h_512
    gemm_tanh_kernel<<<HID / 16, 256, 0, stream>>>(y1, W2, b2, y2);
    logits_kernel<<<(VOCAB + 63) / 64, 256, 0, stream>>>(y2, W3, b3, logits);
    lsm_kernel<<<BATCH, 256, 0, stream>>>(logits, out);
}

// Round 2
// 2996.504 us; speedup vs baseline: 1.1772x; 1.1772x over previous
//
#include <hip/hip_runtime.h>
#include <hip/hip_bf16.h>

#define VOCAB 50257
#define EMBD  256
#define HID   512
#define BATCH 64
#define SEQ   512
#define NG    32     // workgroups per batch-group (each owns 16 h-cols)
#define NGRP  4      // batch groups of 16 rows

typedef short bf16x8 __attribute__((ext_vector_type(8)));
typedef float f32x4  __attribute__((ext_vector_type(4)));

__device__ inline short f2b(float f) {            // RNE float->bf16
    union { float f; unsigned u; } v; v.f = f;
    unsigned r = v.u + 0x7FFFu + ((v.u >> 16) & 1u);
    return (short)(r >> 16);
}
__device__ inline unsigned pack2_trunc(float lo, float hi) {  // 2 floats -> packed bf16x2 (truncate)
    union { float f; unsigned u; } a, b; a.f = lo; b.f = hi;
    return __builtin_amdgcn_perm(b.u, a.u, 0x07060302);
}
__device__ inline float fast_tanh(float x) {
    x = fminf(fmaxf(x, -15.f), 15.f);
    float e = __expf(2.f * x);
    return (e - 1.f) / (e + 1.f);
}
__device__ inline float fast_sig(float x) { return 1.f / (1.f + __expf(-x)); }

__device__ inline void load_x_frags(const float* __restrict__ emb, int idxv, int quad, bf16x8* Ax) {
#pragma unroll
    for (int kt = 0; kt < 8; ++kt) {
        const float* p = emb + (size_t)idxv * EMBD + kt * 32 + quad * 8;
        float4 e0 = *(const float4*)(p);
        float4 e1 = *(const float4*)(p + 4);
        union { bf16x8 v; unsigned u[4]; } f;
        f.u[0] = pack2_trunc(e0.x, e0.y);
        f.u[1] = pack2_trunc(e0.z, e0.w);
        f.u[2] = pack2_trunc(e1.x, e1.y);
        f.u[3] = pack2_trunc(e1.z, e1.w);
        Ax[kt] = f.v;
    }
}

// ---------------------------------------------------------------------------
// Persistent LSTM: 128 WGs = 4 groups (16 batch rows) x 32 WGs (16 h-cols).
// Wave g computes gate g for its 16 cols (register-resident Wh/Wi frags).
// Per-step sync: 64 release-stored flags per group (2 per WG, one per storing
// wave — NO atomic RMW), polled by one wave with one flag per lane.
// ---------------------------------------------------------------------------
__global__ __launch_bounds__(256, 1) void lstm_kernel(
    const int* __restrict__ idx, const float* __restrict__ emb,
    const float* __restrict__ Wi, const float* __restrict__ Wh,
    const float* __restrict__ bvec, unsigned* __restrict__ flags,
    unsigned short* __restrict__ hbuf /* [2][64][512] bf16 */)
{
    const int wgid = blockIdx.x;
    const int grp  = wgid >> 5;
    const int j    = wgid & 31;
    const int tid  = threadIdx.x;
    const int lane = tid & 63;
    const int gate = tid >> 6;         // wave id = gate (i,f,g,o)
    const int quad = lane >> 4;
    const int l16  = lane & 15;
    const int col  = gate * HID + j * 16 + l16;   // gate column in [0,2048)
    const int arow = grp * 16 + l16;              // batch row for A fragments

    __shared__ float gbuf[4][16][16];
    __shared__ float cstate[16][16];
    __shared__ __align__(16) unsigned short hstage[16][HID + 8];  // row stride 1040B (/16 odd -> conflict-free b128 reads)

    cstate[tid >> 4][tid & 15] = 0.f;

    // persistent B fragments: Wh slice (k=512) and Wi slice (k=256), RNE cvt
    bf16x8 Bh[16], Bx[8];
#pragma unroll
    for (int kt = 0; kt < 16; ++kt)
#pragma unroll
        for (int i = 0; i < 8; ++i)
            Bh[kt][i] = f2b(Wh[(size_t)(kt * 32 + quad * 8 + i) * 2048 + col]);
#pragma unroll
    for (int kt = 0; kt < 8; ++kt)
#pragma unroll
        for (int i = 0; i < 8; ++i)
            Bx[kt][i] = f2b(Wi[(size_t)(kt * 32 + quad * 8 + i) * 2048 + col]);
    const float bv = bvec[col];

    bf16x8 Ax[8], Axn[8];
    int idxv = idx[arow * SEQ];
    load_x_frags(emb, idxv, quad, Ax);

    // flags: per group 64 slots, stride 8 dwords (32B). slot = j*2 + storing-wave
    unsigned* const grpflags = flags + grp * 512;
    unsigned* const myflag   = grpflags + ((j * 2 + gate) << 3);   // valid for gate<2

    // staging thread mapping (coalesced 128B-per-16-lanes global reads)
    const int srow = tid >> 4;          // 0..15 (h row)
    const int sch  = tid & 15;          // 16 chunks of 8B per 128B sub-row

    for (int t = 0; t < SEQ; ++t) {
        // ---- x contribution (uses Ax prefetched last step) ----
        f32x4 acc = {0.f, 0.f, 0.f, 0.f};
#pragma unroll
        for (int kt = 0; kt < 8; ++kt)
            acc = __builtin_amdgcn_mfma_f32_16x16x32_bf16(Ax[kt], Bx[kt], acc, 0, 0, 0);

        // ---- issue prefetch of x_{t+1} (hides under h phase / poll) ----
        if (t + 1 < SEQ) {
            int idxn = idx[arow * SEQ + t + 1];
            load_x_frags(emb, idxn, quad, Axn);
        }

        if (t > 0) {
            // ---- poll: wave 0, one flag per lane ----
            if (gate == 0) {
                const unsigned tgt = (unsigned)t;
                unsigned* fp = grpflags + (lane << 3);
                unsigned v;
                do {
                    v = __hip_atomic_load(fp, __ATOMIC_RELAXED, __HIP_MEMORY_SCOPE_AGENT);
                } while (__ballot(v >= tgt) != ~0ull);
            }
            __syncthreads();
            // ---- stage h_t (16x512 bf16) into LDS, coalesced ----
            const unsigned short* hrow = hbuf +
                ((size_t)((t & 1) * BATCH) + grp * 16 + srow) * HID;
            unsigned long long tmp[8];
#pragma unroll
            for (int u = 0; u < 8; ++u)
                tmp[u] = __hip_atomic_load(
                    (const unsigned long long*)(hrow + u * 64 + sch * 4),
                    __ATOMIC_RELAXED, __HIP_MEMORY_SCOPE_AGENT);
#pragma unroll
            for (int u = 0; u < 8; ++u)
                *(unsigned long long*)&hstage[srow][u * 64 + sch * 4] = tmp[u];
            __syncthreads();
            // ---- recurrent MFMAs ----
#pragma unroll
            for (int kt = 0; kt < 16; ++kt) {
                bf16x8 a = *(const bf16x8*)&hstage[l16][kt * 32 + quad * 8];
                acc = __builtin_amdgcn_mfma_f32_16x16x32_bf16(a, Bh[kt], acc, 0, 0, 0);
            }
        }

        // ---- activation: C layout row=(quad*4+r), col=l16 ----
#pragma unroll
        for (int r = 0; r < 4; ++r) {
            float z = acc[r] + bv;
            gbuf[gate][quad * 4 + r][l16] = (gate == 2) ? fast_tanh(z) : fast_sig(z);
        }
        __syncthreads();

        // ---- c/h update by waves 0,1; per-wave release flag (no barrier) ----
        if (tid < 128) {
            const int rr = tid >> 3, c2 = (tid & 7) * 2;
            float h0, h1;
            {
                float i0 = gbuf[0][rr][c2], f0 = gbuf[1][rr][c2];
                float g0 = gbuf[2][rr][c2], o0 = gbuf[3][rr][c2];
                float c = f0 * cstate[rr][c2] + i0 * g0;
                cstate[rr][c2] = c;
                h0 = o0 * fast_tanh(c);
            }
            {
                float i1 = gbuf[0][rr][c2 + 1], f1 = gbuf[1][rr][c2 + 1];
                float g1 = gbuf[2][rr][c2 + 1], o1 = gbuf[3][rr][c2 + 1];
                float c = f1 * cstate[rr][c2 + 1] + i1 * g1;
                cstate[rr][c2 + 1] = c;
                h1 = o1 * fast_tanh(c);
            }
            unsigned pv = (unsigned)(unsigned short)f2b(h0) |
                          ((unsigned)(unsigned short)f2b(h1) << 16);
            unsigned* dst = (unsigned*)(hbuf +
                ((size_t)(((t + 1) & 1) * BATCH) + grp * 16 + rr) * HID + j * 16 + c2);
            __hip_atomic_store(dst, pv, __ATOMIC_RELAXED, __HIP_MEMORY_SCOPE_AGENT);
            if ((tid & 63) == 0)   // lane 0 of each storing wave: release = own-wave vmcnt drain only
                __hip_atomic_store(myflag, (unsigned)(t + 1),
                                   __ATOMIC_RELEASE, __HIP_MEMORY_SCOPE_AGENT);
        }

        // ---- rotate prefetch buffers ----
        if (t + 1 < SEQ) {
#pragma unroll
            for (int kt = 0; kt < 8; ++kt) Ax[kt] = Axn[kt];
        }
    }
}

// ---------------------------------------------------------------------------
// y = tanh(A[64x512](bf16) @ W[512x512](f32) + bias) -> out bf16 [64][512]
// ---------------------------------------------------------------------------
__global__ __launch_bounds__(256, 1) void gemm_tanh_kernel(
    const unsigned short* __restrict__ A, const float* __restrict__ W,
    const float* __restrict__ bias, unsigned short* __restrict__ out)
{
    const int tid = threadIdx.x, lane = tid & 63, wave = tid >> 6;
    const int quad = lane >> 4, l16 = lane & 15;
    const int col = blockIdx.x * 16 + l16;
    bf16x8 Bw[16];
#pragma unroll
    for (int kt = 0; kt < 16; ++kt)
#pragma unroll
        for (int i = 0; i < 8; ++i)
            Bw[kt][i] = f2b(W[(size_t)(kt * 32 + quad * 8 + i) * HID + col]);
    f32x4 acc = {0.f, 0.f, 0.f, 0.f};
#pragma unroll
    for (int kt = 0; kt < 16; ++kt) {
        bf16x8 a = *(const bf16x8*)(A + (size_t)(wave * 16 + l16) * HID + kt * 32 + quad * 8);
        acc = __builtin_amdgcn_mfma_f32_16x16x32_bf16(a, Bw[kt], acc, 0, 0, 0);
    }
    const float bvv = bias[col];
#pragma unroll
    for (int r = 0; r < 4; ++r) {
        float y = fast_tanh(acc[r] + bvv);
        out[(size_t)(wave * 16 + quad * 4 + r) * HID + col] = (unsigned short)f2b(y);
    }
}

// ---------------------------------------------------------------------------
// logits = A[64x512](bf16) @ W3[512x50257](f32) + b3 -> f32 [64][50257]
// LDS-staged W3 tiles: coalesced float4 HBM reads instead of column-strided.
// ---------------------------------------------------------------------------
__global__ __launch_bounds__(256, 2) void logits_kernel(
    const unsigned short* __restrict__ A, const float* __restrict__ W3,
    const float* __restrict__ b3, float* __restrict__ outL)
{
    const int tid = threadIdx.x, lane = tid & 63, wave = tid >> 6;
    const int quad = lane >> 4, l16 = lane & 15;
    const int c0 = blockIdx.x * 64;
    const int col = c0 + wave * 16 + l16;
    const bool cok = col < VOCAB;
    const int colc = cok ? col : (VOCAB - 1);

    __shared__ unsigned short wt[256][68];   // [k][col] bf16, pad 4 shorts

    f32x4 acc[4];
#pragma unroll
    for (int rt = 0; rt < 4; ++rt) acc[rt] = (f32x4){0.f, 0.f, 0.f, 0.f};

    const int kr = tid >> 4;          // staging row within 16-row pass
    const int cg = (tid & 15) * 4;    // 4-col group

    for (int kc = 0; kc < 2; ++kc) {
#pragma unroll 4
        for (int it = 0; it < 16; ++it) {
            const int k = it * 16 + kr;
            const int gc = c0 + cg;
            float4 wv;
            if (gc + 3 < VOCAB) {
                wv = *(const float4*)&W3[(size_t)(kc * 256 + k) * VOCAB + gc];
            } else {
                const float* Wr = &W3[(size_t)(kc * 256 + k) * VOCAB];
                wv.x = (gc + 0 < VOCAB) ? Wr[gc + 0] : 0.f;
                wv.y = (gc + 1 < VOCAB) ? Wr[gc + 1] : 0.f;
                wv.z = (gc + 2 < VOCAB) ? Wr[gc + 2] : 0.f;
                wv.w = (gc + 3 < VOCAB) ? Wr[gc + 3] : 0.f;
            }
            unsigned short* d = &wt[k][cg];
            d[0] = (unsigned short)f2b(wv.x);
            d[1] = (unsigned short)f2b(wv.y);
            d[2] = (unsigned short)f2b(wv.z);
            d[3] = (unsigned short)f2b(wv.w);
        }
        __syncthreads();
        bf16x8 Bw[8];
#pragma unroll
        for (int kt = 0; kt < 8; ++kt)
#pragma unroll
            for (int i = 0; i < 8; ++i)
                Bw[kt][i] = (short)wt[kt * 32 + quad * 8 + i][wave * 16 + l16];
#pragma unroll
        for (int rt = 0; rt < 4; ++rt)
#pragma unroll
            for (int kt = 0; kt < 8; ++kt) {
                bf16x8 a = *(const bf16x8*)(A + (size_t)(rt * 16 + l16) * HID +
                                            kc * 256 + kt * 32 + quad * 8);
                acc[rt] = __builtin_amdgcn_mfma_f32_16x16x32_bf16(a, Bw[kt], acc[rt], 0, 0, 0);
            }
        __syncthreads();
    }
    const float bvv = b3[colc];
    if (cok) {
#pragma unroll
        for (int rt = 0; rt < 4; ++rt)
#pragma unroll
            for (int r = 0; r < 4; ++r)
                outL[(size_t)(rt * 16 + quad * 4 + r) * VOCAB + col] = acc[rt][r] + bvv;
    }
}

// ---------------------------------------------------------------------------
// row-wise log_softmax over [64][50257], float4 main loop (50256 = 12564*4)
// ---------------------------------------------------------------------------
__global__ __launch_bounds__(256, 1) void lsm_kernel(
    const float* __restrict__ lg, float* __restrict__ out)
{
    const int row = blockIdx.x;
    const float* L = lg + (size_t)row * VOCAB;
    const float4* L4 = (const float4*)L;
    const int nv4 = VOCAB / 4;   // 12564, tail element = 50256

    float m = -1e30f;
    for (int i = threadIdx.x; i < nv4; i += 256) {
        float4 v = L4[i];
        m = fmaxf(fmaxf(fmaxf(m, v.x), fmaxf(v.y, v.z)), v.w);
    }
    if (threadIdx.x == 0) m = fmaxf(m, L[VOCAB - 1]);
#pragma unroll
    for (int o = 32; o; o >>= 1) m = fmaxf(m, __shfl_xor(m, o));
    __shared__ float red[4], red2[4];
    if ((threadIdx.x & 63) == 0) red[threadIdx.x >> 6] = m;
    __syncthreads();
    m = fmaxf(fmaxf(red[0], red[1]), fmaxf(red[2], red[3]));

    float s = 0.f;
    for (int i = threadIdx.x; i < nv4; i += 256) {
        float4 v = L4[i];
        s += __expf(v.x - m) + __expf(v.y - m) + __expf(v.z - m) + __expf(v.w - m);
    }
    if (threadIdx.x == 0) s += __expf(L[VOCAB - 1] - m);
#pragma unroll
    for (int o = 32; o; o >>= 1) s += __shfl_xor(s, o);
    if ((threadIdx.x & 63) == 0) red2[threadIdx.x >> 6] = s;
    __syncthreads();
    s = red2[0] + red2[1] + red2[2] + red2[3];
    const float ls = m + __logf(s);

    float* O = out + (size_t)row * VOCAB;
    float4* O4 = (float4*)O;
    for (int i = threadIdx.x; i < nv4; i += 256) {
        float4 v = L4[i];
        O4[i] = (float4){v.x - ls, v.y - ls, v.z - ls, v.w - ls};
    }
    if (threadIdx.x == 0) O[VOCAB - 1] = L[VOCAB - 1] - ls;
}

extern "C" void kernel_launch(void* const* d_in, const int* in_sizes, int n_in,
                              void* d_out, int out_size, void* d_ws, size_t ws_size,
                              hipStream_t stream) {
    (void)in_sizes; (void)n_in; (void)out_size; (void)ws_size;
    const int*   idx = (const int*)d_in[0];
    const float* emb = (const float*)d_in[1];
    const float* Wi  = (const float*)d_in[2];
    const float* Wh  = (const float*)d_in[3];
    const float* b   = (const float*)d_in[4];
    const float* W1  = (const float*)d_in[5];
    const float* b1  = (const float*)d_in[6];
    const float* W2  = (const float*)d_in[7];
    const float* b2  = (const float*)d_in[8];
    const float* W3  = (const float*)d_in[9];
    const float* b3  = (const float*)d_in[10];
    float* out = (float*)d_out;

    char* w = (char*)d_ws;
    unsigned*       flags  = (unsigned*)w;                                // 8 KiB (4 grp x 64 x 32B)
    unsigned short* hbuf   = (unsigned short*)(w + 8192);                 // 128 KiB
    unsigned short* y1     = (unsigned short*)(w + 8192 + 131072);        // 64 KiB
    unsigned short* y2     = (unsigned short*)(w + 8192 + 131072 + 65536);// 64 KiB
    float*          logits = (float*)(w + 8192 + 131072 + 131072);        // 12.9 MB

    (void)hipMemsetAsync(flags, 0, 8192, stream);
    lstm_kernel<<<NGRP * NG, 256, 0, stream>>>(idx, emb, Wi, Wh, b, flags, hbuf);
    gemm_tanh_kernel<<<HID / 16, 256, 0, stream>>>(hbuf, W1, b1, y1);  // hbuf slot 0 = h_final
    gemm_tanh_kernel<<<HID / 16, 256, 0, stream>>>(y1, W2, b2, y2);
    logits_kernel<<<(VOCAB + 63) / 64, 256, 0, stream>>>(y2, W3, b3, logits);
    lsm_kernel<<<BATCH, 256, 0, stream>>>(logits, out);
}